// Round 21
// baseline (676.963 us; speedup 1.0000x reference)
//
#include <hip/hip_runtime.h>

#define TSEQ 512
#define NTH  1024   // 16 waves, ONE block/CU: 0-7 layer0, 8-15 layer1 (skew 2)
// R21 (from best=R20): 4 waves/SIMD via single 1024-thread block, work-neutral.
// Each layer = 8 waves; wave owns an 8-unit slice via TWO dual-gate M-tiles
// (tile0 = gates{0,1} x 8 units, tile1 = gates{2,3}). After MFMA, 8x
// shfl_xor(32) exchanges gate halves; pair-split activation (2 units/lane)
// keeps per-CU trans/VALU/MFMA totals identical to R20. Per-wave: L0 6 MFMA,
// L1 8 MFMA -> 4 short chains per SIMD hide each other's latency tails.

typedef __attribute__((ext_vector_type(8))) _Float16 half8;
typedef __attribute__((ext_vector_type(4))) float f32x4;
typedef __attribute__((ext_vector_type(4))) unsigned int u32x4;

__device__ __forceinline__ unsigned pkrtz(float a, float b) {
    return __builtin_bit_cast(unsigned, __builtin_amdgcn_cvt_pkrtz(a, b));
}
// init-time RNE pack (not hot)
__device__ __forceinline__ unsigned packF16x2(float a, float b) {
    _Float16 ha = (_Float16)a, hb = (_Float16)b;
    return (unsigned)__builtin_bit_cast(unsigned short, ha) |
           ((unsigned)__builtin_bit_cast(unsigned short, hb) << 16);
}
__device__ __forceinline__ half8 packA16s(const float* w8, float s) {
    u32x4 W = { packF16x2(w8[0]*s, w8[1]*s), packF16x2(w8[2]*s, w8[3]*s),
                packF16x2(w8[4]*s, w8[5]*s), packF16x2(w8[6]*s, w8[7]*s) };
    return __builtin_bit_cast(half8, W);
}

#define MFMA(a, b, c) __builtin_amdgcn_mfma_f32_16x16x32_f16((a), (b), (c), 0, 0, 0)
#define LD128H(p) __builtin_bit_cast(half8, *(const u32x4*)(p))
#define EXP2(v) __builtin_amdgcn_exp2f(v)
#define RCP(v)  __builtin_amdgcn_rcpf(v)

// fused LSTM unit update with PRE-SCALED pre-acts (scales folded into W/b):
// a_i,a_f,a_o = -log2e * preact;  a_g = 2*log2e * preact
__device__ __forceinline__ float act_fused(float ai, float af, float ag, float ao, float* c) {
    const float L2E2 = 2.88539008177792681472f;
    float ei = EXP2(ai);
    float ef = EXP2(af);
    float eg = EXP2(ag);
    float eo = EXP2(ao);
    float sf = RCP(1.0f + ef);
    float ig = (eg - 1.0f) * RCP((1.0f + ei) * (eg + 1.0f));
    float cn = fmaf(*c, sf, ig);
    *c = cn;
    float ec = EXP2(cn * L2E2);
    return (ec - 1.0f) * RCP((1.0f + eo) * (ec + 1.0f));
}

__global__ __launch_bounds__(NTH, 1)
void lstm2_mfma(const float* __restrict__ x,
                const float* __restrict__ W_ih0, const float* __restrict__ W_hh0,
                const float* __restrict__ b_ih0, const float* __restrict__ b_hh0,
                const float* __restrict__ W_ih1, const float* __restrict__ W_hh1,
                const float* __restrict__ b_ih1, const float* __restrict__ b_hh1,
                const float* __restrict__ W_fc,  const float* __restrict__ b_fc,
                float* __restrict__ out)
{
    const int tid  = threadIdx.x;
    const int lane = tid & 63;
    const int wv   = tid >> 6;        // 0-7: layer0, 8-15: layer1
    const int rl   = lane & 15;       // MFMA row/col index = batch col n
    const int g    = lane >> 4;       // k-group 0..3
    const int gsel = g >> 1;          // which gate-half this lane OWNS after exchange
    const int gand = g & 1;           // unit sub-offset
    const int b0   = blockIdx.x * 16;
    const int w    = wv & 7;          // unit-octet: units [8w, 8w+8)

    const float NL2E  = -1.44269504088896340736f;  // i,f,o row scale
    const float PL2E2 =  2.88539008177792681472f;  // g row scale

    // f16 h planes (2 units/word), depth-2 ping-pong. h[t] at parity (t+1)&1.
    __shared__ unsigned h0P0[512], h0P1[512];
    __shared__ unsigned h1P0[512], h1P1[512];
    __shared__ float fcl[64 * 17];    // padded 16->17

    for (int i2 = tid; i2 < 512; i2 += NTH) {
        h0P0[i2] = 0u; h0P1[i2] = 0u; h1P0[i2] = 0u; h1P1[i2] = 0u;
    }
    __syncthreads();

    // diagonal-swizzle b128 read offsets (loop-invariant)
    const int offL = rl*32 + (((g + rl) & 7) << 2);         // k-half 0
    const int offH = rl*32 + (((4 + g + rl) & 7) << 2);     // k-half 1
    // write word (unit-pair) this lane owns: units U0=8w+4*gand+2*gsel, U0+1
    const int q    = 4*w + 2*gand + gsel;
    const int woff = rl*32 + ((((q >> 2) + rl) & 7) << 2) + (q & 3);
    const int U0   = 8*w + 4*gand + 2*gsel;

    // dual-gate M-tile row mapping: tile T covers gates {2T, 2T+1} x units [8w,8w+8)
    // A-frag row for lane: rowT = 64*(2T + (rl>>3)) + 8w + (rl&7)

    if (wv < 8) {
        // ======== LAYER 0 ========
        half8 A0[2][2];   // [tile][k-half of W_hh0]
        half8 Ax[2];      // [tile] x-term: k0-3 = W_ih0 row (g==0 lanes), else 0
        f32x4 bias4[2];   // [tile] C-init
        #pragma unroll
        for (int T = 0; T < 2; ++T) {
            const int gateA = 2*T + (rl >> 3);
            const float sc  = (gateA == 2) ? PL2E2 : NL2E;
            const int rowA  = 64*gateA + 8*w + (rl & 7);
            #pragma unroll
            for (int s = 0; s < 2; ++s)
                A0[T][s] = packA16s(W_hh0 + rowA*64 + s*32 + g*8, sc);
            {
                u32x4 ax = {0u, 0u, 0u, 0u};
                if (g == 0) {
                    ax.x = packF16x2(W_ih0[rowA*4+0]*sc, W_ih0[rowA*4+1]*sc);
                    ax.y = packF16x2(W_ih0[rowA*4+2]*sc, W_ih0[rowA*4+3]*sc);
                }
                Ax[T] = __builtin_bit_cast(half8, ax);
            }
            const int gateC = 2*T + gsel;
            const float scb = (gateC == 2) ? PL2E2 : NL2E;
            const int rowC  = 64*gateC + 8*w + 4*gand;   // + j
            bias4[T].x = (b_ih0[rowC+0] + b_hh0[rowC+0]) * scb;
            bias4[T].y = (b_ih0[rowC+1] + b_hh0[rowC+1]) * scb;
            bias4[T].z = (b_ih0[rowC+2] + b_hh0[rowC+2]) * scb;
            bias4[T].w = (b_ih0[rowC+3] + b_hh0[rowC+3]) * scb;
        }
        float cst[2] = {0.f, 0.f};

        // prologue: x[0] load + pre-pack (col rl)
        f32x4 xf = *(const f32x4*)(x + ((size_t)(b0 + rl) * TSEQ) * 4);
        unsigned bx0 = pkrtz(xf.x, xf.y);
        unsigned bx1 = pkrtz(xf.z, xf.w);

        auto body0 = [&](const unsigned* rP, unsigned* wP, int i) {
            if (i + 1 < TSEQ)
                xf = *(const f32x4*)(x + ((size_t)(b0 + rl) * TSEQ + (i + 1)) * 4);

            half8 B0 = LD128H(rP + offL);
            half8 B1 = LD128H(rP + offH);
            u32x4 tx = {0u, 0u, 0u, 0u};
            if (g == 0) { tx.x = bx0; tx.y = bx1; }
            half8 Bx = __builtin_bit_cast(half8, tx);

            f32x4 a0, a1;
            a0 = MFMA(Ax[0], Bx, bias4[0]);   a1 = MFMA(Ax[1], Bx, bias4[1]);
            a0 = MFMA(A0[0][0], B0, a0);      a1 = MFMA(A0[1][0], B0, a1);
            a0 = MFMA(A0[0][1], B1, a0);      a1 = MFMA(A0[1][1], B1, a1);

            // gate-half exchange: partner lane = lane ^ 32 (gsel flips)
            float p0[4], p1[4];
            #pragma unroll
            for (int j = 0; j < 4; ++j) {
                p0[j] = __shfl_xor(a0[j], 32);
                p1[j] = __shfl_xor(a1[j], 32);
            }
            float hv[2];
            #pragma unroll
            for (int k = 0; k < 2; ++k) {
                const int j = 2*gsel + k;
                float G0 = gsel ? p0[j] : a0[j];
                float G1 = gsel ? a0[j] : p0[j];
                float G2 = gsel ? p1[j] : a1[j];
                float G3 = gsel ? a1[j] : p1[j];
                hv[k] = act_fused(G0, G1, G2, G3, &cst[k]);
            }

            bx0 = pkrtz(xf.x, xf.y);
            bx1 = pkrtz(xf.z, xf.w);

            wP[woff] = pkrtz(hv[0], hv[1]);
        };

        for (int ii = 0; ii < 256; ++ii) {
            body0(h0P0, h0P1, 2*ii);     __syncthreads();  // i=2ii   (p=0)
            body0(h0P1, h0P0, 2*ii + 1); __syncthreads();  // i=2ii+1 (p=1)
        }
        __syncthreads();   // i=512 slot (L1 tail)
        __syncthreads();   // i=513 slot (L1 tail)
    } else {
        // ======== LAYER 1 (skew 2): iter i computes t=i-2; h0 prefetched at i-1 ========
        half8 A1[2][4];   // [tile][s]: s=0,1 W_ih1 (vs h0); s=2,3 W_hh1 (vs h1)
        f32x4 bias4[2];
        #pragma unroll
        for (int T = 0; T < 2; ++T) {
            const int gateA = 2*T + (rl >> 3);
            const float sc  = (gateA == 2) ? PL2E2 : NL2E;
            const int rowA  = 64*gateA + 8*w + (rl & 7);
            #pragma unroll
            for (int s = 0; s < 4; ++s) {
                const float* src = (s < 2) ? (W_ih1 + rowA*64 + s*32 + g*8)
                                           : (W_hh1 + rowA*64 + (s-2)*32 + g*8);
                A1[T][s] = packA16s(src, sc);
            }
            const int gateC = 2*T + gsel;
            const float scb = (gateC == 2) ? PL2E2 : NL2E;
            const int rowC  = 64*gateC + 8*w + 4*gand;
            bias4[T].x = (b_ih1[rowC+0] + b_hh1[rowC+0]) * scb;
            bias4[T].y = (b_ih1[rowC+1] + b_hh1[rowC+1]) * scb;
            bias4[T].z = (b_ih1[rowC+2] + b_hh1[rowC+2]) * scb;
            bias4[T].w = (b_ih1[rowC+3] + b_hh1[rowC+3]) * scb;
        }
        float cst[2] = {0.f, 0.f};

        half8 pB0 = {}, pB1 = {};   // prefetched h0[t] frags

        auto body1 = [&](const unsigned* r1P, unsigned* wP,
                         const unsigned* n0P, bool wrFC) {
            half8 B2 = LD128H(r1P + offL);
            half8 B3 = LD128H(r1P + offH);

            f32x4 a0, a1;
            a0 = MFMA(A1[0][0], pB0, bias4[0]);   a1 = MFMA(A1[1][0], pB0, bias4[1]);
            a0 = MFMA(A1[0][1], pB1, a0);         a1 = MFMA(A1[1][1], pB1, a1);
            a0 = MFMA(A1[0][2], B2, a0);          a1 = MFMA(A1[1][2], B2, a1);
            a0 = MFMA(A1[0][3], B3, a0);          a1 = MFMA(A1[1][3], B3, a1);

            // prefetch h0[t+1]: latency hides under exchange+act tail
            pB0 = LD128H(n0P + offL);
            pB1 = LD128H(n0P + offH);

            float p0[4], p1[4];
            #pragma unroll
            for (int j = 0; j < 4; ++j) {
                p0[j] = __shfl_xor(a0[j], 32);
                p1[j] = __shfl_xor(a1[j], 32);
            }
            float hv[2];
            #pragma unroll
            for (int k = 0; k < 2; ++k) {
                const int j = 2*gsel + k;
                float G0 = gsel ? p0[j] : a0[j];
                float G1 = gsel ? a0[j] : p0[j];
                float G2 = gsel ? p1[j] : a1[j];
                float G3 = gsel ? a1[j] : p1[j];
                hv[k] = act_fused(G0, G1, G2, G3, &cst[k]);
            }
            wP[woff] = pkrtz(hv[0], hv[1]);
            if (wrFC) {
                fcl[(U0 + 0)*17 + rl] = hv[0];
                fcl[(U0 + 1)*17 + rl] = hv[1];
            }
        };

        __syncthreads();                         // i=0 (idle)
        // i=1: prefetch-only — h0[0] lives at parity 1
        pB0 = LD128H(h0P1 + offL);
        pB1 = LD128H(h0P1 + offH);
        __syncthreads();                         // i=1
        for (int ii = 0; ii < 256; ++ii) {
            body1(h1P0, h1P1, h0P0, false);     __syncthreads();  // i=2+2ii (p=0)
            body1(h1P1, h1P0, h0P1, ii == 255); __syncthreads();  // i=3+2ii (p=1)
        }
    }

    // ---- FC: out[b] = h1_last[b,:] . W_fc + b_fc ----
    if (tid < 16) {
        float acc = b_fc[0];
        #pragma unroll 16
        for (int u = 0; u < 64; ++u) acc += fcl[u*17 + tid] * W_fc[u];
        out[b0 + tid] = acc;
    }
}

extern "C" void kernel_launch(void* const* d_in, const int* in_sizes, int n_in,
                              void* d_out, int out_size, void* d_ws, size_t ws_size,
                              hipStream_t stream) {
    const float* x     = (const float*)d_in[0];
    const float* W_ih0 = (const float*)d_in[1];
    const float* W_hh0 = (const float*)d_in[2];
    const float* b_ih0 = (const float*)d_in[3];
    const float* b_hh0 = (const float*)d_in[4];
    const float* W_ih1 = (const float*)d_in[5];
    const float* W_hh1 = (const float*)d_in[6];
    const float* b_ih1 = (const float*)d_in[7];
    const float* b_hh1 = (const float*)d_in[8];
    const float* W_fc  = (const float*)d_in[9];
    const float* b_fc  = (const float*)d_in[10];
    float* out = (float*)d_out;

    dim3 grid(4096 / 16), block(NTH);
    hipLaunchKernelGGL(lstm2_mfma, grid, block, 0, stream,
                       x, W_ih0, W_hh0, b_ih0, b_hh0,
                       W_ih1, W_hh1, b_ih1, b_hh1, W_fc, b_fc, out);
}